// Round 3
// baseline (225.305 us; speedup 1.0000x reference)
//
#include <hip/hip_runtime.h>

#define NC    91
#define DM    64
#define CIN   128
#define NMOV  4206

// LDS pitches (floats)
#define HP    68     // 64-wide activation rows
#define QP    196    // qkv rows (192 + pad)
#define F1P   132    // ff1 output rows (128 + pad)
#define FEP   136    // feats rows (128 + pad, 16B-aligned)
#define WP64  65     // staged weight rows, 64 cols
#define WP128 130    // staged weight rows, 128 cols
#define GP    92     // gram matrix pitch

__constant__ int HEXOFF[NC] = {
  55,66,77,88,99,110,
  45,56,67,78,89,100,111,
  35,46,57,68,79,90,101,112,
  25,36,47,58,69,80,91,102,113,
  15,26,37,48,59,70,81,92,103,114,
  5,16,27,38,49,60,71,82,93,104,115,
  6,17,28,39,50,61,72,83,94,105,
  7,18,29,40,51,62,73,84,95,
  8,19,30,41,52,63,74,85,
  9,20,31,42,53,64,75,
  10,21,32,43,54,65
};

#define DOT64(ACC, SPTR, W) do { \
  _Pragma("unroll") \
  for (int k4_ = 0; k4_ < 16; ++k4_) { \
    float4 f_ = *(const float4*)((SPTR) + 4*k4_); \
    ACC = fmaf(f_.x, W[4*k4_+0], ACC); \
    ACC = fmaf(f_.y, W[4*k4_+1], ACC); \
    ACC = fmaf(f_.z, W[4*k4_+2], ACC); \
    ACC = fmaf(f_.w, W[4*k4_+3], ACC); \
  } } while(0)

#define DOT128(ACC, SPTR, W) do { \
  _Pragma("unroll") \
  for (int k4_ = 0; k4_ < 32; ++k4_) { \
    float4 f_ = *(const float4*)((SPTR) + 4*k4_); \
    ACC = fmaf(f_.x, W[4*k4_+0], ACC); \
    ACC = fmaf(f_.y, W[4*k4_+1], ACC); \
    ACC = fmaf(f_.z, W[4*k4_+2], ACC); \
    ACC = fmaf(f_.w, W[4*k4_+3], ACC); \
  } } while(0)

__global__ __launch_bounds__(512, 2)
void policy_fused(
    const float* __restrict__ x,
    const float* __restrict__ embed_w, const float* __restrict__ embed_b,
    const float* __restrict__ pos,
    const float* __restrict__ in_w,  const float* __restrict__ in_b,
    const float* __restrict__ out_w, const float* __restrict__ out_b,
    const float* __restrict__ ln1_g, const float* __restrict__ ln1_b,
    const float* __restrict__ ln2_g, const float* __restrict__ ln2_b,
    const float* __restrict__ ff1_w, const float* __restrict__ ff1_b,
    const float* __restrict__ ff2_w, const float* __restrict__ ff2_b,
    const float* __restrict__ from_w, const float* __restrict__ from_b,
    const float* __restrict__ to_w,  const float* __restrict__ to_b,
    const float* __restrict__ move_bias,
    const int* __restrict__ move_from, const int* __restrict__ move_to,
    float* __restrict__ out)
{
  __shared__ float hbuf[NC*HP];     // residual stream h           (24.2 KB)
  __shared__ float bbuf[NC*HP];     // hn / attn-out / hn2         (24.2 KB)
  __shared__ float car[NC*QP];      // feats / qkv / f1 / F,T^T    (69.7 KB)
  __shared__ float wslot[DM*132];   // staged weights / gram G     (33.0 KB)

  const int tid  = threadIdx.x;
  const int lane = tid & 63;
  const int wid  = tid >> 6;
  const int b    = blockIdx.x;
  const float* xb = x + (size_t)b * (CIN*121);

  // ---------------- stage 0: hex-gather feats + stage embed_w ----------------
  for (int e = tid; e < NC*CIN; e += 512) {
    int c = e / NC;
    int i = e - c*NC;
    car[i*FEP + c] = xb[c*121 + HEXOFF[i]];
  }
  for (int e = tid; e < DM*CIN; e += 512) {
    int r = e >> 7, c = e & 127;
    wslot[r*WP128 + c] = embed_w[e];
  }
  __syncthreads();

  // ---------------- stage 1: embed: h = feats @ Wt + b + pos ----------------
  {
    float w[CIN];
    #pragma unroll
    for (int d = 0; d < CIN; ++d) w[d] = wslot[lane*WP128 + d];
    const float eb = embed_b[lane];
    for (int i = wid; i < NC; i += 8) {
      float acc = eb + pos[i*DM + lane];
      DOT128(acc, &car[i*FEP], w);
      hbuf[i*HP + lane] = acc;
    }
  }
  __syncthreads();

  // ---------------- LN1: hbuf -> bbuf ----------------
  {
    const float g = ln1_g[lane], bb = ln1_b[lane];
    for (int i = wid; i < NC; i += 8) {
      float v = hbuf[i*HP + lane];
      float s = v, sq = v*v;
      #pragma unroll
      for (int off = 32; off >= 1; off >>= 1) {
        s  += __shfl_xor(s, off, 64);
        sq += __shfl_xor(sq, off, 64);
      }
      float m  = s * (1.0f/64.0f);
      float vr = sq * (1.0f/64.0f) - m*m;
      float rs = rsqrtf(vr + 1e-5f);
      bbuf[i*HP + lane] = (v - m) * rs * g + bb;
    }
  }
  __syncthreads();

  // ---------------- qkv = hn @ in_w.T + in_b  (3 chunks of 64) ----------------
  for (int cc = 0; cc < 3; ++cc) {
    for (int e = tid; e < DM*DM; e += 512) {
      int r = e >> 6, d = e & 63;
      wslot[r*WP64 + d] = in_w[(cc*DM + r)*DM + d];
    }
    __syncthreads();
    float w[DM];
    #pragma unroll
    for (int d = 0; d < DM; ++d) w[d] = wslot[lane*WP64 + d];
    const float bia = in_b[cc*DM + lane];
    for (int i = wid; i < NC; i += 8) {
      float acc = bia;
      DOT64(acc, &bbuf[i*HP], w);
      car[i*QP + cc*DM + lane] = acc;
    }
    __syncthreads();
  }

  // ---------------- attention: one thread per (head, query), online softmax ----
  {
    const int p = tid;
    if (p < 4*NC) {
      const int h = p / NC;
      const int i = p - h*NC;
      const float* qr = &car[i*QP + h*16];
      float4 qa = *(const float4*)(qr+0),  qb = *(const float4*)(qr+4),
             qc = *(const float4*)(qr+8),  qd = *(const float4*)(qr+12);
      float4 oa = {0,0,0,0}, obv = {0,0,0,0}, ocv = {0,0,0,0}, odv = {0,0,0,0};
      float mrun = -3.0e38f, lrun = 0.0f;
      for (int j = 0; j < NC; ++j) {
        const float* kr = &car[j*QP + DM + h*16];
        float4 ka = *(const float4*)(kr+0), kb = *(const float4*)(kr+4),
               kc = *(const float4*)(kr+8), kd = *(const float4*)(kr+12);
        float s = qa.x*ka.x + qa.y*ka.y + qa.z*ka.z + qa.w*ka.w;
        s += qb.x*kb.x + qb.y*kb.y + qb.z*kb.z + qb.w*kb.w;
        s += qc.x*kc.x + qc.y*kc.y + qc.z*kc.z + qc.w*kc.w;
        s += qd.x*kd.x + qd.y*kd.y + qd.z*kd.z + qd.w*kd.w;
        s *= 0.25f;
        float mn = fmaxf(mrun, s);
        float sc = __expf(mrun - mn);
        float pw = __expf(s - mn);
        lrun = lrun*sc + pw;
        const float* vr = &car[j*QP + 2*DM + h*16];
        float4 va = *(const float4*)(vr+0), vb = *(const float4*)(vr+4),
               vc = *(const float4*)(vr+8), vd = *(const float4*)(vr+12);
        oa.x = oa.x*sc + pw*va.x;  oa.y = oa.y*sc + pw*va.y;
        oa.z = oa.z*sc + pw*va.z;  oa.w = oa.w*sc + pw*va.w;
        obv.x = obv.x*sc + pw*vb.x; obv.y = obv.y*sc + pw*vb.y;
        obv.z = obv.z*sc + pw*vb.z; obv.w = obv.w*sc + pw*vb.w;
        ocv.x = ocv.x*sc + pw*vc.x; ocv.y = ocv.y*sc + pw*vc.y;
        ocv.z = ocv.z*sc + pw*vc.z; ocv.w = ocv.w*sc + pw*vc.w;
        odv.x = odv.x*sc + pw*vd.x; odv.y = odv.y*sc + pw*vd.y;
        odv.z = odv.z*sc + pw*vd.z; odv.w = odv.w*sc + pw*vd.w;
        mrun = mn;
      }
      float inv = 1.0f / lrun;
      float* orow = &bbuf[i*HP + h*16];
      *(float4*)(orow+0)  = make_float4(oa.x*inv,  oa.y*inv,  oa.z*inv,  oa.w*inv);
      *(float4*)(orow+4)  = make_float4(obv.x*inv, obv.y*inv, obv.z*inv, obv.w*inv);
      *(float4*)(orow+8)  = make_float4(ocv.x*inv, ocv.y*inv, ocv.z*inv, ocv.w*inv);
      *(float4*)(orow+12) = make_float4(odv.x*inv, odv.y*inv, odv.z*inv, odv.w*inv);
    }
  }
  __syncthreads();

  // ---------------- out-proj: h += o @ out_w.T + out_b ----------------
  for (int e = tid; e < DM*DM; e += 512) {
    int r = e >> 6, d = e & 63;
    wslot[r*WP64 + d] = out_w[e];
  }
  __syncthreads();
  {
    float w[DM];
    #pragma unroll
    for (int d = 0; d < DM; ++d) w[d] = wslot[lane*WP64 + d];
    const float obias = out_b[lane];
    for (int i = wid; i < NC; i += 8) {
      float acc = obias;
      DOT64(acc, &bbuf[i*HP], w);
      hbuf[i*HP + lane] += acc;
    }
  }
  __syncthreads();

  // ---------------- LN2: hbuf -> bbuf ----------------
  {
    const float g = ln2_g[lane], bb = ln2_b[lane];
    for (int i = wid; i < NC; i += 8) {
      float v = hbuf[i*HP + lane];
      float s = v, sq = v*v;
      #pragma unroll
      for (int off = 32; off >= 1; off >>= 1) {
        s  += __shfl_xor(s, off, 64);
        sq += __shfl_xor(sq, off, 64);
      }
      float m  = s * (1.0f/64.0f);
      float vr = sq * (1.0f/64.0f) - m*m;
      float rs = rsqrtf(vr + 1e-5f);
      bbuf[i*HP + lane] = (v - m) * rs * g + bb;
    }
  }
  __syncthreads();

  // ---------------- ff1: f1 = relu(hn2 @ ff1_w.T + b)  (2 chunks) ----------------
  for (int ec = 0; ec < 2; ++ec) {
    for (int e = tid; e < DM*DM; e += 512) {
      int r = e >> 6, d = e & 63;
      wslot[r*WP64 + d] = ff1_w[(ec*DM + r)*DM + d];
    }
    __syncthreads();
    float w[DM];
    #pragma unroll
    for (int d = 0; d < DM; ++d) w[d] = wslot[lane*WP64 + d];
    const float bia = ff1_b[ec*DM + lane];
    for (int i = wid; i < NC; i += 8) {
      float acc = bia;
      DOT64(acc, &bbuf[i*HP], w);
      car[i*F1P + ec*DM + lane] = fmaxf(acc, 0.0f);
    }
    __syncthreads();
  }

  // ---------------- ff2: h += f1 @ ff2_w.T + b ----------------
  for (int e = tid; e < DM*CIN; e += 512) {
    int r = e >> 7, c = e & 127;
    wslot[r*WP128 + c] = ff2_w[e];
  }
  __syncthreads();
  {
    float w[CIN];
    #pragma unroll
    for (int d = 0; d < CIN; ++d) w[d] = wslot[lane*WP128 + d];
    const float bia = ff2_b[lane];
    for (int i = wid; i < NC; i += 8) {
      float acc = bia;
      DOT128(acc, &car[i*F1P], w);
      hbuf[i*HP + lane] += acc;
    }
  }
  __syncthreads();

  // ---------------- from_feats -> car[0..], row-major ----------------
  for (int e = tid; e < DM*DM; e += 512) {
    int r = e >> 6, d = e & 63;
    wslot[r*WP64 + d] = from_w[e];
  }
  __syncthreads();
  {
    float w[DM];
    #pragma unroll
    for (int d = 0; d < DM; ++d) w[d] = wslot[lane*WP64 + d];
    const float bia = from_b[lane];
    for (int i = wid; i < NC; i += 8) {
      float acc = bia;
      DOT64(acc, &hbuf[i*HP], w);
      car[i*HP + lane] = acc;
    }
  }
  __syncthreads();

  // ---------------- to_feats -> car[NC*HP..], transposed [d][j] ----------------
  for (int e = tid; e < DM*DM; e += 512) {
    int r = e >> 6, d = e & 63;
    wslot[r*WP64 + d] = to_w[e];
  }
  __syncthreads();
  {
    float w[DM];
    #pragma unroll
    for (int d = 0; d < DM; ++d) w[d] = wslot[lane*WP64 + d];
    const float bia = to_b[lane];
    for (int i = wid; i < NC; i += 8) {
      float acc = bia;
      DOT64(acc, &hbuf[i*HP], w);
      car[NC*HP + lane*GP + i] = acc;   // T^T[d][j]
    }
  }
  __syncthreads();

  // ---------------- Gram: G[i][j] = F[i] . T[j] -> wslot ----------------
  {
    const float* tfT = &car[NC*HP];
    for (int i = wid; i < NC; i += 8) {
      const float* fr = &car[i*HP];
      #pragma unroll
      for (int jp = 0; jp < 2; ++jp) {
        int j = jp*64 + lane;
        if (j < NC) {
          float acc = 0.0f;
          #pragma unroll
          for (int k4 = 0; k4 < 16; ++k4) {
            float4 f = *(const float4*)(fr + 4*k4);
            acc = fmaf(f.x, tfT[(4*k4+0)*GP + j], acc);
            acc = fmaf(f.y, tfT[(4*k4+1)*GP + j], acc);
            acc = fmaf(f.z, tfT[(4*k4+2)*GP + j], acc);
            acc = fmaf(f.w, tfT[(4*k4+3)*GP + j], acc);
          }
          wslot[i*GP + j] = acc;
        }
      }
    }
  }
  __syncthreads();

  // ---------------- logits: gather from G ----------------
  {
    float* ob = out + (size_t)b * NMOV;
    for (int m = tid; m < NMOV; m += 512) {
      ob[m] = wslot[move_from[m]*GP + move_to[m]] + move_bias[m];
    }
  }
}

extern "C" void kernel_launch(void* const* d_in, const int* in_sizes, int n_in,
                              void* d_out, int out_size, void* d_ws, size_t ws_size,
                              hipStream_t stream) {
  const float* x        = (const float*)d_in[0];
  const float* embed_w  = (const float*)d_in[1];
  const float* embed_b  = (const float*)d_in[2];
  const float* pos      = (const float*)d_in[3];
  const float* in_w     = (const float*)d_in[4];
  const float* in_b     = (const float*)d_in[5];
  const float* out_w    = (const float*)d_in[6];
  const float* out_b    = (const float*)d_in[7];
  const float* ln1_g    = (const float*)d_in[8];
  const float* ln1_b    = (const float*)d_in[9];
  const float* ln2_g    = (const float*)d_in[10];
  const float* ln2_b    = (const float*)d_in[11];
  const float* ff1_w    = (const float*)d_in[12];
  const float* ff1_b    = (const float*)d_in[13];
  const float* ff2_w    = (const float*)d_in[14];
  const float* ff2_b    = (const float*)d_in[15];
  const float* from_w   = (const float*)d_in[16];
  const float* from_b   = (const float*)d_in[17];
  const float* to_w     = (const float*)d_in[18];
  const float* to_b     = (const float*)d_in[19];
  const float* move_bias= (const float*)d_in[20];
  const int*   move_from= (const int*)d_in[21];
  const int*   move_to  = (const int*)d_in[22];

  int B = in_sizes[0] / (CIN * 121);
  policy_fused<<<dim3(B), dim3(512), 0, stream>>>(
      x, embed_w, embed_b, pos, in_w, in_b, out_w, out_b,
      ln1_g, ln1_b, ln2_g, ln2_b, ff1_w, ff1_b, ff2_w, ff2_b,
      from_w, from_b, to_w, to_b, move_bias, move_from, move_to,
      (float*)d_out);
}

// Round 4
// 189.319 us; speedup vs baseline: 1.1901x; 1.1901x over previous
//
#include <hip/hip_runtime.h>

#define NC    91
#define DM    64
#define CIN   128
#define NMOV  4206

// LDS pitches (floats) — all row pitches are multiples of 4 => 16B-aligned rows
#define HP    68     // 64-wide activation rows (68*4=272B, 16B-aligned)
#define QP    196    // qkv rows (192 + pad, 784B)
#define F1P   132    // ff1 output rows (528B)
#define FEP   136    // feats rows (544B)
#define WP64  68     // staged weight rows, 64 cols (272B, 16B-aligned)
#define WP128 132    // staged weight rows, 128 cols (528B, 16B-aligned)
#define GP    92     // gram matrix pitch (368B)
#define WSLOT 8704   // 128*WP64 floats (fits 2x 64-row W64, 1x 64-row W128, 91x92 G)

__constant__ int HEXOFF[NC] = {
  55,66,77,88,99,110,
  45,56,67,78,89,100,111,
  35,46,57,68,79,90,101,112,
  25,36,47,58,69,80,91,102,113,
  15,26,37,48,59,70,81,92,103,114,
  5,16,27,38,49,60,71,82,93,104,115,
  6,17,28,39,50,61,72,83,94,105,
  7,18,29,40,51,62,73,84,95,
  8,19,30,41,52,63,74,85,
  9,20,31,42,53,64,75,
  10,21,32,43,54,65
};

// 64-dot: activations via wave-uniform float4 LDS broadcasts, weights in VGPRs,
// 4 independent accumulator chains.
__device__ __forceinline__ float dot64(const float* sp, const float4* W) {
  float a0 = 0.f, a1 = 0.f, a2 = 0.f, a3 = 0.f;
  #pragma unroll
  for (int k = 0; k < 16; ++k) {
    float4 f = *(const float4*)(sp + 4*k);
    a0 = fmaf(f.x, W[k].x, a0);
    a1 = fmaf(f.y, W[k].y, a1);
    a2 = fmaf(f.z, W[k].z, a2);
    a3 = fmaf(f.w, W[k].w, a3);
  }
  return (a0 + a1) + (a2 + a3);
}

// two 64-dots sharing one activation read pass
__device__ __forceinline__ float2 dot64x2(const float* sp, const float4* W0, const float4* W1) {
  float a0=0.f,a1=0.f,a2=0.f,a3=0.f, b0=0.f,b1=0.f,b2=0.f,b3=0.f;
  #pragma unroll
  for (int k = 0; k < 16; ++k) {
    float4 f = *(const float4*)(sp + 4*k);
    a0 = fmaf(f.x, W0[k].x, a0);
    a1 = fmaf(f.y, W0[k].y, a1);
    a2 = fmaf(f.z, W0[k].z, a2);
    a3 = fmaf(f.w, W0[k].w, a3);
    b0 = fmaf(f.x, W1[k].x, b0);
    b1 = fmaf(f.y, W1[k].y, b1);
    b2 = fmaf(f.z, W1[k].z, b2);
    b3 = fmaf(f.w, W1[k].w, b3);
  }
  return make_float2((a0+a1)+(a2+a3), (b0+b1)+(b2+b3));
}

__device__ __forceinline__ float dot128(const float* sp, const float4* W) {
  float a0 = 0.f, a1 = 0.f, a2 = 0.f, a3 = 0.f;
  #pragma unroll
  for (int k = 0; k < 32; ++k) {
    float4 f = *(const float4*)(sp + 4*k);
    a0 = fmaf(f.x, W[k].x, a0);
    a1 = fmaf(f.y, W[k].y, a1);
    a2 = fmaf(f.z, W[k].z, a2);
    a3 = fmaf(f.w, W[k].w, a3);
  }
  return (a0 + a1) + (a2 + a3);
}

#define LOADW16(W, BASE) do { \
  _Pragma("unroll") \
  for (int k_ = 0; k_ < 16; ++k_) W[k_] = *(const float4*)((BASE) + 4*k_); \
} while (0)

#define LOADW32(W, BASE) do { \
  _Pragma("unroll") \
  for (int k_ = 0; k_ < 32; ++k_) W[k_] = *(const float4*)((BASE) + 4*k_); \
} while (0)

__global__ __launch_bounds__(512, 2)
void policy_fused(
    const float* __restrict__ x,
    const float* __restrict__ embed_w, const float* __restrict__ embed_b,
    const float* __restrict__ pos,
    const float* __restrict__ in_w,  const float* __restrict__ in_b,
    const float* __restrict__ out_w, const float* __restrict__ out_b,
    const float* __restrict__ ln1_g, const float* __restrict__ ln1_b,
    const float* __restrict__ ln2_g, const float* __restrict__ ln2_b,
    const float* __restrict__ ff1_w, const float* __restrict__ ff1_b,
    const float* __restrict__ ff2_w, const float* __restrict__ ff2_b,
    const float* __restrict__ from_w, const float* __restrict__ from_b,
    const float* __restrict__ to_w,  const float* __restrict__ to_b,
    const float* __restrict__ move_bias,
    const int* __restrict__ move_from, const int* __restrict__ move_to,
    float* __restrict__ out)
{
  __shared__ float hbuf[NC*HP];     // residual stream h            (24.7 KB)
  __shared__ float bbuf[NC*HP];     // hn / attn-out / hn2          (24.7 KB)
  __shared__ float car[NC*QP];      // feats / qkv / f1 / F,T^T     (69.7 KB)
  __shared__ float wslot[WSLOT];    // staged weights / gram G      (34.8 KB)

  const int tid  = threadIdx.x;
  const int lane = tid & 63;
  const int wid  = tid >> 6;
  const int b    = blockIdx.x;
  const float* xb = x + (size_t)b * (CIN*121);

  // ---- P0: hex-gather feats + stage embed_w (64x128 @ WP128) ----
  for (int e = tid; e < NC*CIN; e += 512) {
    int c = e / NC;
    int i = e - c*NC;
    car[i*FEP + c] = xb[c*121 + HEXOFF[i]];
  }
  for (int e = tid; e < DM*CIN; e += 512) {
    int r = e >> 7, c = e & 127;
    wslot[r*WP128 + c] = embed_w[e];
  }
  __syncthreads();

  // ---- P1: embed: h = feats @ Wt + b + pos ----
  {
    float4 W[32];
    LOADW32(W, &wslot[lane*WP128]);
    const float eb = embed_b[lane];
    for (int i = wid; i < NC; i += 8) {
      float acc = dot128(&car[i*FEP], W);
      hbuf[i*HP + lane] = acc + eb + pos[i*DM + lane];
    }
  }
  __syncthreads();

  // ---- P2: LN1 (hbuf->bbuf) + stage q,k weights (in_w rows 0..127) ----
  for (int e = tid; e < 2*DM*DM; e += 512) {
    int r = e >> 6, d = e & 63;
    wslot[r*WP64 + d] = in_w[e];
  }
  {
    const float g = ln1_g[lane], bb = ln1_b[lane];
    for (int i = wid; i < NC; i += 8) {
      float v = hbuf[i*HP + lane];
      float s = v, sq = v*v;
      #pragma unroll
      for (int off = 32; off >= 1; off >>= 1) {
        s  += __shfl_xor(s, off, 64);
        sq += __shfl_xor(sq, off, 64);
      }
      float m  = s * (1.0f/64.0f);
      float vr = sq * (1.0f/64.0f) - m*m;
      float rs = rsqrtf(vr + 1e-5f);
      bbuf[i*HP + lane] = (v - m) * rs * g + bb;
    }
  }
  __syncthreads();

  // ---- P3: q,k = hn @ {Wq,Wk}^T + b ----
  {
    float4 W0[16], W1[16];
    LOADW16(W0, &wslot[lane*WP64]);
    LOADW16(W1, &wslot[(DM + lane)*WP64]);
    const float bq = in_b[lane], bk = in_b[DM + lane];
    for (int i = wid; i < NC; i += 8) {
      float2 r = dot64x2(&bbuf[i*HP], W0, W1);
      car[i*QP + lane]      = r.x + bq;
      car[i*QP + DM + lane] = r.y + bk;
    }
  }
  __syncthreads();

  // ---- P4: stage v weights (in_w rows 128..191) ----
  for (int e = tid; e < DM*DM; e += 512) {
    int r = e >> 6, d = e & 63;
    wslot[r*WP64 + d] = in_w[2*DM*DM + e];
  }
  __syncthreads();

  // ---- P5: v = hn @ Wv^T + b ----
  {
    float4 W[16];
    LOADW16(W, &wslot[lane*WP64]);
    const float bv = in_b[2*DM + lane];
    for (int i = wid; i < NC; i += 8) {
      car[i*QP + 2*DM + lane] = dot64(&bbuf[i*HP], W) + bv;
    }
  }
  __syncthreads();

  // ---- P6: attention (threads 0..363) + stage out_w (all threads) ----
  for (int e = tid; e < DM*DM; e += 512) {
    int r = e >> 6, d = e & 63;
    wslot[r*WP64 + d] = out_w[e];
  }
  {
    const int p = tid;
    if (p < 4*NC) {
      const int h = p / NC;
      const int i = p - h*NC;
      const float* qr = &car[i*QP + h*16];
      float4 qa = *(const float4*)(qr+0),  qb = *(const float4*)(qr+4),
             qc = *(const float4*)(qr+8),  qd = *(const float4*)(qr+12);
      float4 oa = {0,0,0,0}, obv = {0,0,0,0}, ocv = {0,0,0,0}, odv = {0,0,0,0};
      float mrun = -3.0e38f, lrun = 0.0f;
      for (int j = 0; j < NC; ++j) {
        const float* kr = &car[j*QP + DM + h*16];
        float4 ka = *(const float4*)(kr+0), kb = *(const float4*)(kr+4),
               kc = *(const float4*)(kr+8), kd = *(const float4*)(kr+12);
        // 4 independent product chains
        float t0 = fmaf(qa.w,ka.w, fmaf(qa.z,ka.z, fmaf(qa.y,ka.y, qa.x*ka.x)));
        float t1 = fmaf(qb.w,kb.w, fmaf(qb.z,kb.z, fmaf(qb.y,kb.y, qb.x*kb.x)));
        float t2 = fmaf(qc.w,kc.w, fmaf(qc.z,kc.z, fmaf(qc.y,kc.y, qc.x*kc.x)));
        float t3 = fmaf(qd.w,kd.w, fmaf(qd.z,kd.z, fmaf(qd.y,kd.y, qd.x*kd.x)));
        float s = ((t0+t1)+(t2+t3)) * 0.25f;
        float mn = fmaxf(mrun, s);
        float sc = __expf(mrun - mn);
        float pw = __expf(s - mn);
        lrun = lrun*sc + pw;
        const float* vr = &car[j*QP + 2*DM + h*16];
        float4 va = *(const float4*)(vr+0), vb = *(const float4*)(vr+4),
               vc = *(const float4*)(vr+8), vd = *(const float4*)(vr+12);
        oa.x = oa.x*sc + pw*va.x;  oa.y = oa.y*sc + pw*va.y;
        oa.z = oa.z*sc + pw*va.z;  oa.w = oa.w*sc + pw*va.w;
        obv.x = obv.x*sc + pw*vb.x; obv.y = obv.y*sc + pw*vb.y;
        obv.z = obv.z*sc + pw*vb.z; obv.w = obv.w*sc + pw*vb.w;
        ocv.x = ocv.x*sc + pw*vc.x; ocv.y = ocv.y*sc + pw*vc.y;
        ocv.z = ocv.z*sc + pw*vc.z; ocv.w = ocv.w*sc + pw*vc.w;
        odv.x = odv.x*sc + pw*vd.x; odv.y = odv.y*sc + pw*vd.y;
        odv.z = odv.z*sc + pw*vd.z; odv.w = odv.w*sc + pw*vd.w;
        mrun = mn;
      }
      float inv = 1.0f / lrun;
      float* orow = &bbuf[i*HP + h*16];
      *(float4*)(orow+0)  = make_float4(oa.x*inv,  oa.y*inv,  oa.z*inv,  oa.w*inv);
      *(float4*)(orow+4)  = make_float4(obv.x*inv, obv.y*inv, obv.z*inv, obv.w*inv);
      *(float4*)(orow+8)  = make_float4(ocv.x*inv, ocv.y*inv, ocv.z*inv, ocv.w*inv);
      *(float4*)(orow+12) = make_float4(odv.x*inv, odv.y*inv, odv.z*inv, odv.w*inv);
    }
  }
  __syncthreads();

  // ---- P7: out-proj: h += o @ out_w^T + out_b ----
  {
    float4 W[16];
    LOADW16(W, &wslot[lane*WP64]);
    const float obias = out_b[lane];
    for (int i = wid; i < NC; i += 8) {
      hbuf[i*HP + lane] += dot64(&bbuf[i*HP], W) + obias;
    }
  }
  __syncthreads();

  // ---- P8: LN2 (hbuf->bbuf) + stage ff1 both chunks (128x64 @ WP64) ----
  for (int e = tid; e < 2*DM*DM; e += 512) {
    int r = e >> 6, d = e & 63;
    wslot[r*WP64 + d] = ff1_w[e];
  }
  {
    const float g = ln2_g[lane], bb = ln2_b[lane];
    for (int i = wid; i < NC; i += 8) {
      float v = hbuf[i*HP + lane];
      float s = v, sq = v*v;
      #pragma unroll
      for (int off = 32; off >= 1; off >>= 1) {
        s  += __shfl_xor(s, off, 64);
        sq += __shfl_xor(sq, off, 64);
      }
      float m  = s * (1.0f/64.0f);
      float vr = sq * (1.0f/64.0f) - m*m;
      float rs = rsqrtf(vr + 1e-5f);
      bbuf[i*HP + lane] = (v - m) * rs * g + bb;
    }
  }
  __syncthreads();

  // ---- P9: ff1 both chunks: f1 = relu(hn2 @ ff1_w^T + b) ----
  {
    float4 W0[16], W1[16];
    LOADW16(W0, &wslot[lane*WP64]);
    LOADW16(W1, &wslot[(DM + lane)*WP64]);
    const float b0 = ff1_b[lane], b1 = ff1_b[DM + lane];
    for (int i = wid; i < NC; i += 8) {
      float2 r = dot64x2(&bbuf[i*HP], W0, W1);
      car[i*F1P + lane]      = fmaxf(r.x + b0, 0.0f);
      car[i*F1P + DM + lane] = fmaxf(r.y + b1, 0.0f);
    }
  }
  __syncthreads();

  // ---- P10: stage ff2 (64x128 @ WP128) ----
  for (int e = tid; e < DM*CIN; e += 512) {
    int r = e >> 7, c = e & 127;
    wslot[r*WP128 + c] = ff2_w[e];
  }
  __syncthreads();

  // ---- P11: ff2: h += f1 @ ff2_w^T + b ----
  {
    float4 W[32];
    LOADW32(W, &wslot[lane*WP128]);
    const float bia = ff2_b[lane];
    for (int i = wid; i < NC; i += 8) {
      hbuf[i*HP + lane] += dot128(&car[i*F1P], W) + bia;
    }
  }
  __syncthreads();

  // ---- P12: stage from_w + to_w (rows 0..63 from, 64..127 to) ----
  for (int e = tid; e < 2*DM*DM; e += 512) {
    int r = e >> 6, d = e & 63;
    wslot[r*WP64 + d] = (r < DM) ? from_w[r*DM + d] : to_w[(r-DM)*DM + d];
  }
  __syncthreads();

  // ---- P13: from/to merged: F rows + T^T[d][j] ----
  {
    float4 W0[16], W1[16];
    LOADW16(W0, &wslot[lane*WP64]);
    LOADW16(W1, &wslot[(DM + lane)*WP64]);
    const float bf = from_b[lane], bt = to_b[lane];
    for (int i = wid; i < NC; i += 8) {
      float2 r = dot64x2(&hbuf[i*HP], W0, W1);
      car[i*HP + lane] = r.x + bf;              // F row-major
      car[NC*HP + lane*GP + i] = r.y + bt;      // T^T[d][j]
    }
  }
  __syncthreads();

  // ---- P14: Gram: G[i][j] = F[i] . T[j] -> wslot ----
  {
    const float* tfT = &car[NC*HP];
    for (int i = wid; i < NC; i += 8) {
      const float* fr = &car[i*HP];
      #pragma unroll
      for (int jp = 0; jp < 2; ++jp) {
        int j = jp*64 + lane;
        if (j < NC) {
          float a0 = 0.f, a1 = 0.f;
          #pragma unroll
          for (int k4 = 0; k4 < 16; ++k4) {
            float4 f = *(const float4*)(fr + 4*k4);
            a0 = fmaf(f.x, tfT[(4*k4+0)*GP + j], a0);
            a1 = fmaf(f.y, tfT[(4*k4+1)*GP + j], a1);
            a0 = fmaf(f.z, tfT[(4*k4+2)*GP + j], a0);
            a1 = fmaf(f.w, tfT[(4*k4+3)*GP + j], a1);
          }
          wslot[i*GP + j] = a0 + a1;
        }
      }
    }
  }
  __syncthreads();

  // ---- P15: logits gather ----
  {
    float* ob = out + (size_t)b * NMOV;
    for (int m = tid; m < NMOV; m += 512) {
      ob[m] = wslot[move_from[m]*GP + move_to[m]] + move_bias[m];
    }
  }
}

extern "C" void kernel_launch(void* const* d_in, const int* in_sizes, int n_in,
                              void* d_out, int out_size, void* d_ws, size_t ws_size,
                              hipStream_t stream) {
  const float* x        = (const float*)d_in[0];
  const float* embed_w  = (const float*)d_in[1];
  const float* embed_b  = (const float*)d_in[2];
  const float* pos      = (const float*)d_in[3];
  const float* in_w     = (const float*)d_in[4];
  const float* in_b     = (const float*)d_in[5];
  const float* out_w    = (const float*)d_in[6];
  const float* out_b    = (const float*)d_in[7];
  const float* ln1_g    = (const float*)d_in[8];
  const float* ln1_b    = (const float*)d_in[9];
  const float* ln2_g    = (const float*)d_in[10];
  const float* ln2_b    = (const float*)d_in[11];
  const float* ff1_w    = (const float*)d_in[12];
  const float* ff1_b    = (const float*)d_in[13];
  const float* ff2_w    = (const float*)d_in[14];
  const float* ff2_b    = (const float*)d_in[15];
  const float* from_w   = (const float*)d_in[16];
  const float* from_b   = (const float*)d_in[17];
  const float* to_w     = (const float*)d_in[18];
  const float* to_b     = (const float*)d_in[19];
  const float* move_bias= (const float*)d_in[20];
  const int*   move_from= (const int*)d_in[21];
  const int*   move_to  = (const int*)d_in[22];

  int B = in_sizes[0] / (CIN * 121);
  policy_fused<<<dim3(B), dim3(512), 0, stream>>>(
      x, embed_w, embed_b, pos, in_w, in_b, out_w, out_b,
      ln1_g, ln1_b, ln2_g, ln2_b, ff1_w, ff1_b, ff2_w, ff2_b,
      from_w, from_b, to_w, to_b, move_bias, move_from, move_to,
      (float*)d_out);
}

// Round 5
// 103.387 us; speedup vs baseline: 2.1792x; 1.8312x over previous
//
#include <hip/hip_runtime.h>
#include <hip/hip_bf16.h>

typedef __attribute__((ext_vector_type(8))) short short8;
typedef __attribute__((ext_vector_type(4))) float f32x4;

#define NC    91
#define DM    64
#define CIN   128
#define NMOV  4206
#define MR    96      // row-padded (6 x 16)
#define HP    68      // hbuf fp32 pitch
#define QP    196     // qkv fp32 pitch
#define GP    96      // gram fp32 pitch

__constant__ int HEXOFF[NC] = {
  55,66,77,88,99,110,
  45,56,67,78,89,100,111,
  35,46,57,68,79,90,101,112,
  25,36,47,58,69,80,91,102,113,
  15,26,37,48,59,70,81,92,103,114,
  5,16,27,38,49,60,71,82,93,104,115,
  6,17,28,39,50,61,72,83,94,105,
  7,18,29,40,51,62,73,84,95,
  8,19,30,41,52,63,74,85,
  9,20,31,42,53,64,75,
  10,21,32,43,54,65
};

// byte offset into a bf16 buffer with PB bytes/row; 16B-slot XOR swizzle by row&7
#define SWZ(row, col, PB) ((row)*(PB) + ((((((col)*2)>>4)) ^ ((row)&7)) << 4) + (((col)*2)&15))

__device__ __forceinline__ short f2bf(float f) {
  __hip_bfloat16 h = __float2bfloat16(f);
  return __builtin_bit_cast(short, h);
}

__device__ __forceinline__ short8 ldfrag128(const short* buf, int row, int k0) {
  return *(const short8*)((const char*)buf + SWZ(row, k0, 128));
}
__device__ __forceinline__ short8 ldfrag256(const short* buf, int row, int k0) {
  return *(const short8*)((const char*)buf + SWZ(row, k0, 256));
}
__device__ __forceinline__ void stb16_128(short* buf, int row, int col, float v) {
  *(short*)((char*)buf + SWZ(row, col, 128)) = f2bf(v);
}
__device__ __forceinline__ void stb16_256(short* buf, int row, int col, float v) {
  *(short*)((char*)buf + SWZ(row, col, 256)) = f2bf(v);
}

__global__ __launch_bounds__(512, 2)
void policy_fused(
    const float* __restrict__ x,
    const float* __restrict__ embed_w, const float* __restrict__ embed_b,
    const float* __restrict__ pos,
    const float* __restrict__ in_w,  const float* __restrict__ in_b,
    const float* __restrict__ out_w, const float* __restrict__ out_b,
    const float* __restrict__ ln1_g, const float* __restrict__ ln1_b,
    const float* __restrict__ ln2_g, const float* __restrict__ ln2_b,
    const float* __restrict__ ff1_w, const float* __restrict__ ff1_b,
    const float* __restrict__ ff2_w, const float* __restrict__ ff2_b,
    const float* __restrict__ from_w, const float* __restrict__ from_b,
    const float* __restrict__ to_w,  const float* __restrict__ to_b,
    const float* __restrict__ move_bias,
    const int* __restrict__ move_from, const int* __restrict__ move_to,
    float* __restrict__ out)
{
  __shared__ float hbuf[MR*HP];      // residual h fp32               26112 B
  __shared__ float arena[18816];     // feats16/qkv/f1/F,T,G          75264 B
  __shared__ short ab16[MR*64];      // bf16 A-staging (swz, PB=128)  12288 B
  __shared__ short wA[192*64];       // weights bf16 (swz, PB=128)    24576 B
  __shared__ short wB[64*128];       // weights bf16 (swz, PB=256)    16384 B

  const int tid  = threadIdx.x;
  const int lane = tid & 63;
  const int wid  = tid >> 6;
  const int l15  = lane & 15;
  const int kfr  = (lane >> 4) * 8;   // k offset within a 32-wide k-chunk
  const int mfr  = (lane >> 4) * 4;   // C-frag row offset
  const int b    = blockIdx.x;
  const float* xb = x + (size_t)b * (CIN*121);

  // ---- P0: hex-gather feats -> bf16 arena ; stage embed_w -> wB ----
  short* featsb = (short*)arena;                 // [96][128] bf16 swz PB=256
  for (int e = tid; e < NC*CIN; e += 512) {
    int c = e / NC, i = e - c*NC;
    stb16_256(featsb, i, c, xb[c*121 + HEXOFF[i]]);
  }
  for (int e = tid; e < DM*CIN; e += 512) {      // embed_w [64][128]
    int r = e >> 7, c = e & 127;
    stb16_256(wB, r, c, embed_w[e]);
  }
  __syncthreads();

  // ---- P1: embed MFMA (K=128) -> hbuf fp32 ; stage in_w -> wA ----
  for (int e = tid; e < 3*DM*DM; e += 512) {     // in_w [192][64]
    int r = e >> 6, c = e & 63;
    stb16_128(wA, r, c, in_w[e]);
  }
  for (int t = wid; t < 24; t += 8) {
    int mt = t >> 2, nt = t & 3;
    int ar = mt*16 + l15, br = nt*16 + l15;
    f32x4 acc = {0.f,0.f,0.f,0.f};
    #pragma unroll
    for (int kk = 0; kk < 4; ++kk) {
      short8 a = ldfrag256(featsb, ar, kk*32 + kfr);
      short8 w = ldfrag256(wB,      br, kk*32 + kfr);
      acc = __builtin_amdgcn_mfma_f32_16x16x32_bf16(a, w, acc, 0, 0, 0);
    }
    int col = nt*16 + l15;
    float eb = embed_b[col];
    #pragma unroll
    for (int i2 = 0; i2 < 4; ++i2) {
      int m = mt*16 + mfr + i2;
      float p = (m < NC) ? pos[m*DM + col] : 0.f;
      hbuf[m*HP + col] = acc[i2] + eb + p;
    }
  }
  __syncthreads();

  // ---- P2: LN1 -> ab16 bf16 ; stage out_w -> wB(PB=128 region) ----
  for (int e = tid; e < DM*DM; e += 512) {
    int r = e >> 6, c = e & 63;
    stb16_128((short*)wB, r, c, out_w[e]);
  }
  {
    const float g = ln1_g[lane], bb = ln1_b[lane];
    for (int i = wid; i < NC; i += 8) {
      float v = hbuf[i*HP + lane];
      float s = v, sq = v*v;
      #pragma unroll
      for (int off = 32; off >= 1; off >>= 1) {
        s  += __shfl_xor(s, off, 64);
        sq += __shfl_xor(sq, off, 64);
      }
      float m  = s * (1.0f/64.0f);
      float vr = sq * (1.0f/64.0f) - m*m;
      float rs = rsqrtf(vr + 1e-5f);
      stb16_128(ab16, i, lane, (v - m) * rs * g + bb);
    }
  }
  __syncthreads();

  // ---- P3: qkv MFMA (N=192, K=64) -> qkv fp32 in arena ----
  float* qkv = arena;                             // [96][196] fp32
  for (int t = wid; t < 72; t += 8) {
    int mt = t / 12, nt = t - mt*12;
    int ar = mt*16 + l15, br = nt*16 + l15;
    f32x4 acc = {0.f,0.f,0.f,0.f};
    #pragma unroll
    for (int kk = 0; kk < 2; ++kk) {
      short8 a = ldfrag128(ab16, ar, kk*32 + kfr);
      short8 w = ldfrag128(wA,   br, kk*32 + kfr);
      acc = __builtin_amdgcn_mfma_f32_16x16x32_bf16(a, w, acc, 0, 0, 0);
    }
    int col = nt*16 + l15;
    float bia = in_b[col];
    #pragma unroll
    for (int i2 = 0; i2 < 4; ++i2)
      qkv[(mt*16 + mfr + i2)*QP + col] = acc[i2] + bia;
  }
  __syncthreads();

  // ---- P4: attention (threads 0..363) -> o bf16 in ab16 ; stage ff1 -> wA ----
  for (int e = tid; e < 2*DM*DM; e += 512) {      // ff1_w [128][64]
    int r = e >> 6, c = e & 63;
    stb16_128(wA, r, c, ff1_w[e]);
  }
  {
    const int p = tid;
    if (p < 4*NC) {
      const int h = p / NC;
      const int i = p - h*NC;
      const float* qr = &qkv[i*QP + h*16];
      float4 qa = *(const float4*)(qr+0),  qb = *(const float4*)(qr+4),
             qc = *(const float4*)(qr+8),  qd = *(const float4*)(qr+12);
      float4 oa = {0,0,0,0}, obv = {0,0,0,0}, ocv = {0,0,0,0}, odv = {0,0,0,0};
      float mrun = -3.0e38f, lrun = 0.0f;
      for (int j = 0; j < NC; ++j) {
        const float* kr = &qkv[j*QP + DM + h*16];
        float4 ka = *(const float4*)(kr+0), kb = *(const float4*)(kr+4),
               kc = *(const float4*)(kr+8), kd = *(const float4*)(kr+12);
        float t0 = fmaf(qa.w,ka.w, fmaf(qa.z,ka.z, fmaf(qa.y,ka.y, qa.x*ka.x)));
        float t1 = fmaf(qb.w,kb.w, fmaf(qb.z,kb.z, fmaf(qb.y,kb.y, qb.x*kb.x)));
        float t2 = fmaf(qc.w,kc.w, fmaf(qc.z,kc.z, fmaf(qc.y,kc.y, qc.x*kc.x)));
        float t3 = fmaf(qd.w,kd.w, fmaf(qd.z,kd.z, fmaf(qd.y,kd.y, qd.x*kd.x)));
        float s = ((t0+t1)+(t2+t3)) * 0.25f;
        float mn = fmaxf(mrun, s);
        float sc = __expf(mrun - mn);
        float pw = __expf(s - mn);
        lrun = lrun*sc + pw;
        const float* vr = &qkv[j*QP + 2*DM + h*16];
        float4 va = *(const float4*)(vr+0), vb = *(const float4*)(vr+4),
               vc = *(const float4*)(vr+8), vd = *(const float4*)(vr+12);
        oa.x = oa.x*sc + pw*va.x;  oa.y = oa.y*sc + pw*va.y;
        oa.z = oa.z*sc + pw*va.z;  oa.w = oa.w*sc + pw*va.w;
        obv.x = obv.x*sc + pw*vb.x; obv.y = obv.y*sc + pw*vb.y;
        obv.z = obv.z*sc + pw*vb.z; obv.w = obv.w*sc + pw*vb.w;
        ocv.x = ocv.x*sc + pw*vc.x; ocv.y = ocv.y*sc + pw*vc.y;
        ocv.z = ocv.z*sc + pw*vc.z; ocv.w = ocv.w*sc + pw*vc.w;
        odv.x = odv.x*sc + pw*vd.x; odv.y = odv.y*sc + pw*vd.y;
        odv.z = odv.z*sc + pw*vd.z; odv.w = odv.w*sc + pw*vd.w;
        mrun = mn;
      }
      float inv = 1.0f / lrun;
      short8 o0, o1;
      o0[0]=f2bf(oa.x*inv);  o0[1]=f2bf(oa.y*inv);  o0[2]=f2bf(oa.z*inv);  o0[3]=f2bf(oa.w*inv);
      o0[4]=f2bf(obv.x*inv); o0[5]=f2bf(obv.y*inv); o0[6]=f2bf(obv.z*inv); o0[7]=f2bf(obv.w*inv);
      o1[0]=f2bf(ocv.x*inv); o1[1]=f2bf(ocv.y*inv); o1[2]=f2bf(ocv.z*inv); o1[3]=f2bf(ocv.w*inv);
      o1[4]=f2bf(odv.x*inv); o1[5]=f2bf(odv.y*inv); o1[6]=f2bf(odv.z*inv); o1[7]=f2bf(odv.w*inv);
      *(short8*)((char*)ab16 + SWZ(i, h*16,     128)) = o0;
      *(short8*)((char*)ab16 + SWZ(i, h*16 + 8, 128)) = o1;
    }
  }
  __syncthreads();

  // ---- P5: out-proj MFMA: hbuf += o @ out_w^T + out_b ----
  for (int t = wid; t < 24; t += 8) {
    int mt = t >> 2, nt = t & 3;
    int ar = mt*16 + l15, br = nt*16 + l15;
    f32x4 acc = {0.f,0.f,0.f,0.f};
    #pragma unroll
    for (int kk = 0; kk < 2; ++kk) {
      short8 a = ldfrag128(ab16,       ar, kk*32 + kfr);
      short8 w = ldfrag128((short*)wB, br, kk*32 + kfr);
      acc = __builtin_amdgcn_mfma_f32_16x16x32_bf16(a, w, acc, 0, 0, 0);
    }
    int col = nt*16 + l15;
    float ob = out_b[col];
    #pragma unroll
    for (int i2 = 0; i2 < 4; ++i2) {
      int m = mt*16 + mfr + i2;
      hbuf[m*HP + col] += acc[i2] + ob;
    }
  }
  __syncthreads();

  // ---- P6: LN2 -> ab16 ; stage ff2 -> wB ----
  for (int e = tid; e < DM*CIN; e += 512) {       // ff2_w [64][128]
    int r = e >> 7, c = e & 127;
    stb16_256(wB, r, c, ff2_w[e]);
  }
  {
    const float g = ln2_g[lane], bb = ln2_b[lane];
    for (int i = wid; i < NC; i += 8) {
      float v = hbuf[i*HP + lane];
      float s = v, sq = v*v;
      #pragma unroll
      for (int off = 32; off >= 1; off >>= 1) {
        s  += __shfl_xor(s, off, 64);
        sq += __shfl_xor(sq, off, 64);
      }
      float m  = s * (1.0f/64.0f);
      float vr = sq * (1.0f/64.0f) - m*m;
      float rs = rsqrtf(vr + 1e-5f);
      stb16_128(ab16, i, lane, (v - m) * rs * g + bb);
    }
  }
  __syncthreads();

  // ---- P7: ff1 MFMA (N=128, K=64) -> f1 bf16 in arena ----
  short* f1 = (short*)arena;                      // [96][128] bf16 swz PB=256
  for (int t = wid; t < 48; t += 8) {
    int mt = t >> 3, nt = t & 7;
    int ar = mt*16 + l15, br = nt*16 + l15;
    f32x4 acc = {0.f,0.f,0.f,0.f};
    #pragma unroll
    for (int kk = 0; kk < 2; ++kk) {
      short8 a = ldfrag128(ab16, ar, kk*32 + kfr);
      short8 w = ldfrag128(wA,   br, kk*32 + kfr);
      acc = __builtin_amdgcn_mfma_f32_16x16x32_bf16(a, w, acc, 0, 0, 0);
    }
    int col = nt*16 + l15;
    float bia = ff1_b[col];
    #pragma unroll
    for (int i2 = 0; i2 < 4; ++i2)
      stb16_256(f1, mt*16 + mfr + i2, col, fmaxf(acc[i2] + bia, 0.f));
  }
  __syncthreads();

  // ---- P9: ff2 MFMA (K=128): h_new = hbuf + f1@W^T + b -> ab16 bf16 ; stage from/to -> wA ----
  for (int e = tid; e < 2*DM*DM; e += 512) {      // [128][64]: rows 0..63 from, 64..127 to
    int r = e >> 6, c = e & 63;
    float v = (r < DM) ? from_w[r*DM + c] : to_w[(r-DM)*DM + c];
    stb16_128(wA, r, c, v);
  }
  for (int t = wid; t < 24; t += 8) {
    int mt = t >> 2, nt = t & 3;
    int ar = mt*16 + l15, br = nt*16 + l15;
    f32x4 acc = {0.f,0.f,0.f,0.f};
    #pragma unroll
    for (int kk = 0; kk < 4; ++kk) {
      short8 a = ldfrag256(f1, ar, kk*32 + kfr);
      short8 w = ldfrag256(wB, br, kk*32 + kfr);
      acc = __builtin_amdgcn_mfma_f32_16x16x32_bf16(a, w, acc, 0, 0, 0);
    }
    int col = nt*16 + l15;
    float bia = ff2_b[col];
    #pragma unroll
    for (int i2 = 0; i2 < 4; ++i2) {
      int m = mt*16 + mfr + i2;
      stb16_128(ab16, m, col, hbuf[m*HP + col] + acc[i2] + bia);
    }
  }
  __syncthreads();

  // ---- P10: from/to MFMA (N=128, K=64) -> F, T bf16 ----
  short* Fb = (short*)arena;                      // [96][64] bf16 swz PB=128
  short* Tb = (short*)arena + 6144;               // [96][64] bf16 swz PB=128
  for (int t = wid; t < 48; t += 8) {
    int mt = t >> 3, nt = t & 7;
    int ar = mt*16 + l15, br = nt*16 + l15;
    f32x4 acc = {0.f,0.f,0.f,0.f};
    #pragma unroll
    for (int kk = 0; kk < 2; ++kk) {
      short8 a = ldfrag128(ab16, ar, kk*32 + kfr);
      short8 w = ldfrag128(wA,   br, kk*32 + kfr);
      acc = __builtin_amdgcn_mfma_f32_16x16x32_bf16(a, w, acc, 0, 0, 0);
    }
    int col = nt*16 + l15;
    if (nt < 4) {
      float bia = from_b[col];
      #pragma unroll
      for (int i2 = 0; i2 < 4; ++i2)
        stb16_128(Fb, mt*16 + mfr + i2, col, acc[i2] + bia);
    } else {
      int c2 = col - 64;
      float bia = to_b[c2];
      #pragma unroll
      for (int i2 = 0; i2 < 4; ++i2)
        stb16_128(Tb, mt*16 + mfr + i2, c2, acc[i2] + bia);
    }
  }
  __syncthreads();

  // ---- P11: gram MFMA: G = F @ T^T (96x96, K=64) ----
  float* G = arena + 6144;                        // [96][96] fp32
  for (int t = wid; t < 36; t += 8) {
    int mt = t / 6, nt = t - mt*6;
    int ar = mt*16 + l15, br = nt*16 + l15;
    f32x4 acc = {0.f,0.f,0.f,0.f};
    #pragma unroll
    for (int kk = 0; kk < 2; ++kk) {
      short8 a = ldfrag128(Fb, ar, kk*32 + kfr);
      short8 w = ldfrag128(Tb, br, kk*32 + kfr);
      acc = __builtin_amdgcn_mfma_f32_16x16x32_bf16(a, w, acc, 0, 0, 0);
    }
    int col = nt*16 + l15;
    #pragma unroll
    for (int i2 = 0; i2 < 4; ++i2)
      G[(mt*16 + mfr + i2)*GP + col] = acc[i2];
  }
  __syncthreads();

  // ---- P12: logits gather ----
  {
    float* ob = out + (size_t)b * NMOV;
    for (int m = tid; m < NMOV; m += 512) {
      ob[m] = G[move_from[m]*GP + move_to[m]] + move_bias[m];
    }
  }
}

extern "C" void kernel_launch(void* const* d_in, const int* in_sizes, int n_in,
                              void* d_out, int out_size, void* d_ws, size_t ws_size,
                              hipStream_t stream) {
  const float* x        = (const float*)d_in[0];
  const float* embed_w  = (const float*)d_in[1];
  const float* embed_b  = (const float*)d_in[2];
  const float* pos      = (const float*)d_in[3];
  const float* in_w     = (const float*)d_in[4];
  const float* in_b     = (const float*)d_in[5];
  const float* out_w    = (const float*)d_in[6];
  const float* out_b    = (const float*)d_in[7];
  const float* ln1_g    = (const float*)d_in[8];
  const float* ln1_b    = (const float*)d_in[9];
  const float* ln2_g    = (const float*)d_in[10];
  const float* ln2_b    = (const float*)d_in[11];
  const float* ff1_w    = (const float*)d_in[12];
  const float* ff1_b    = (const float*)d_in[13];
  const float* ff2_w    = (const float*)d_in[14];
  const float* ff2_b    = (const float*)d_in[15];
  const float* from_w   = (const float*)d_in[16];
  const float* from_b   = (const float*)d_in[17];
  const float* to_w     = (const float*)d_in[18];
  const float* to_b     = (const float*)d_in[19];
  const float* move_bias= (const float*)d_in[20];
  const int*   move_from= (const int*)d_in[21];
  const int*   move_to  = (const int*)d_in[22];

  int B = in_sizes[0] / (CIN * 121);
  policy_fused<<<dim3(B), dim3(512), 0, stream>>>(
      x, embed_w, embed_b, pos, in_w, in_b, out_w, out_b,
      ln1_g, ln1_b, ln2_g, ln2_b, ff1_w, ff1_b, ff2_w, ff2_b,
      from_w, from_b, to_w, to_b, move_bias, move_from, move_to,
      (float*)d_out);
}

// Round 6
// 73.510 us; speedup vs baseline: 3.0650x; 1.4064x over previous
//
#include <hip/hip_runtime.h>
#include <hip/hip_bf16.h>

typedef __attribute__((ext_vector_type(8))) short short8;
typedef __attribute__((ext_vector_type(4))) float f32x4;

#define NC    91
#define DM    64
#define CIN   128
#define NMOV  4206
#define MR    96      // row-padded (6 x 16)
#define HP    68      // hbuf fp32 pitch
#define QP    196     // qkv fp32 pitch
#define GP    96      // gram fp32 pitch
#define NT    1024
#define NW    16

__constant__ int HEXOFF[NC] = {
  55,66,77,88,99,110,
  45,56,67,78,89,100,111,
  35,46,57,68,79,90,101,112,
  25,36,47,58,69,80,91,102,113,
  15,26,37,48,59,70,81,92,103,114,
  5,16,27,38,49,60,71,82,93,104,115,
  6,17,28,39,50,61,72,83,94,105,
  7,18,29,40,51,62,73,84,95,
  8,19,30,41,52,63,74,85,
  9,20,31,42,53,64,75,
  10,21,32,43,54,65
};

// byte offset into a bf16 buffer with PB bytes/row; 16B-slot XOR swizzle by row&7
#define SWZ(row, col, PB) ((row)*(PB) + ((((((col)*2)>>4)) ^ ((row)&7)) << 4) + (((col)*2)&15))

__device__ __forceinline__ short f2bf(float f) {
  __hip_bfloat16 h = __float2bfloat16(f);
  return __builtin_bit_cast(short, h);
}

__device__ __forceinline__ short8 ldfrag128(const short* buf, int row, int k0) {
  return *(const short8*)((const char*)buf + SWZ(row, k0, 128));
}
__device__ __forceinline__ short8 ldfrag256(const short* buf, int row, int k0) {
  return *(const short8*)((const char*)buf + SWZ(row, k0, 256));
}
__device__ __forceinline__ void stb16_128(short* buf, int row, int col, float v) {
  *(short*)((char*)buf + SWZ(row, col, 128)) = f2bf(v);
}

// stage 8 consecutive floats (col multiple of 8) as one swizzled 16B bf16 store
__device__ __forceinline__ void stg8(short* buf, int row, int col, const float* src, int PB) {
  float4 f0 = *(const float4*)(src);
  float4 f1 = *(const float4*)(src + 4);
  short8 v;
  v[0]=f2bf(f0.x); v[1]=f2bf(f0.y); v[2]=f2bf(f0.z); v[3]=f2bf(f0.w);
  v[4]=f2bf(f1.x); v[5]=f2bf(f1.y); v[6]=f2bf(f1.z); v[7]=f2bf(f1.w);
  *(short8*)((char*)buf + (row)*(PB) + (((((col)*2)>>4) ^ ((row)&7)) << 4)) = v;
}

__global__ __launch_bounds__(1024, 1)
void policy_fused(
    const float* __restrict__ x,
    const float* __restrict__ embed_w, const float* __restrict__ embed_b,
    const float* __restrict__ pos,
    const float* __restrict__ in_w,  const float* __restrict__ in_b,
    const float* __restrict__ out_w, const float* __restrict__ out_b,
    const float* __restrict__ ln1_g, const float* __restrict__ ln1_b,
    const float* __restrict__ ln2_g, const float* __restrict__ ln2_b,
    const float* __restrict__ ff1_w, const float* __restrict__ ff1_b,
    const float* __restrict__ ff2_w, const float* __restrict__ ff2_b,
    const float* __restrict__ from_w, const float* __restrict__ from_b,
    const float* __restrict__ to_w,  const float* __restrict__ to_b,
    const float* __restrict__ move_bias,
    const int* __restrict__ move_from, const int* __restrict__ move_to,
    float* __restrict__ out)
{
  __shared__ float hbuf[MR*HP];      // residual h fp32               26112 B
  __shared__ float arena[18816];     // feats16/qkv/f1/F,T,G          75264 B
  __shared__ short ab16[MR*64];      // bf16 A-staging (swz, PB=128)  12288 B
  __shared__ short wA[192*64];       // weights bf16 (swz, PB=128)    24576 B
  __shared__ short wB[64*128];       // weights bf16 (swz, PB=256)    16384 B

  const int tid  = threadIdx.x;
  const int lane = tid & 63;
  const int wid  = tid >> 6;
  const int l15  = lane & 15;
  const int kfr  = (lane >> 4) * 8;   // k offset within a 32-wide k-chunk
  const int mfr  = (lane >> 4) * 4;   // C-frag row offset
  const int b    = blockIdx.x;
  const float* xb = x + (size_t)b * (CIN*121);

  // ---- P0: hex-gather feats -> bf16 arena ; stage embed_w -> wB ----
  short* featsb = (short*)arena;                 // [96][128] bf16 swz PB=256
  for (int e = tid; e < 16*NC; e += NT) {        // 8 channels per item
    int c0 = e / NC, i = e - c0*NC;
    float v[8];
    #pragma unroll
    for (int u = 0; u < 8; ++u) v[u] = xb[(c0*8 + u)*121 + HEXOFF[i]];
    short8 s8;
    #pragma unroll
    for (int u = 0; u < 8; ++u) s8[u] = f2bf(v[u]);
    *(short8*)((char*)featsb + i*256 + ((c0 ^ (i&7)) << 4)) = s8;
  }
  for (int e = tid; e < DM*CIN/8; e += NT) {     // embed_w [64][128]
    int r = e >> 4, c8 = e & 15;
    stg8(wB, r, c8*8, &embed_w[r*CIN + c8*8], 256);
  }
  __syncthreads();

  // ---- P1: embed MFMA (K=128) -> hbuf fp32 ; stage in_w -> wA ----
  for (int e = tid; e < 3*DM*DM/8; e += NT) {    // in_w [192][64]
    int r = e >> 3, c8 = e & 7;
    stg8(wA, r, c8*8, &in_w[r*DM + c8*8], 128);
  }
  for (int t = wid; t < 24; t += NW) {
    int mt = t >> 2, nt = t & 3;
    int ar = mt*16 + l15, br = nt*16 + l15;
    f32x4 acc = {0.f,0.f,0.f,0.f};
    #pragma unroll
    for (int kk = 0; kk < 4; ++kk) {
      short8 a = ldfrag256(featsb, ar, kk*32 + kfr);
      short8 w = ldfrag256(wB,      br, kk*32 + kfr);
      acc = __builtin_amdgcn_mfma_f32_16x16x32_bf16(a, w, acc, 0, 0, 0);
    }
    int col = nt*16 + l15;
    float eb = embed_b[col];
    #pragma unroll
    for (int i2 = 0; i2 < 4; ++i2) {
      int m = mt*16 + mfr + i2;
      float p = (m < NC) ? pos[m*DM + col] : 0.f;
      hbuf[m*HP + col] = acc[i2] + eb + p;
    }
  }
  __syncthreads();

  // ---- P2: LN1 -> ab16 bf16 ; stage out_w -> wB(PB=128 region) ----
  for (int e = tid; e < DM*DM/8; e += NT) {
    int r = e >> 3, c8 = e & 7;
    stg8((short*)wB, r, c8*8, &out_w[r*DM + c8*8], 128);
  }
  {
    const float g = ln1_g[lane & 63], bb = ln1_b[lane & 63];
    for (int i = wid; i < NC; i += NW) {
      float v = hbuf[i*HP + lane];
      float s = v, sq = v*v;
      #pragma unroll
      for (int off = 32; off >= 1; off >>= 1) {
        s  += __shfl_xor(s, off, 64);
        sq += __shfl_xor(sq, off, 64);
      }
      float m  = s * (1.0f/64.0f);
      float vr = sq * (1.0f/64.0f) - m*m;
      float rs = rsqrtf(vr + 1e-5f);
      stb16_128(ab16, i, lane, (v - m) * rs * g + bb);
    }
  }
  __syncthreads();

  // ---- P3: qkv MFMA (N=192, K=64) -> qkv fp32 in arena ----
  float* qkv = arena;                             // [96][196] fp32
  for (int t = wid; t < 72; t += NW) {
    int mt = t / 12, nt = t - mt*12;
    int ar = mt*16 + l15, br = nt*16 + l15;
    f32x4 acc = {0.f,0.f,0.f,0.f};
    #pragma unroll
    for (int kk = 0; kk < 2; ++kk) {
      short8 a = ldfrag128(ab16, ar, kk*32 + kfr);
      short8 w = ldfrag128(wA,   br, kk*32 + kfr);
      acc = __builtin_amdgcn_mfma_f32_16x16x32_bf16(a, w, acc, 0, 0, 0);
    }
    int col = nt*16 + l15;
    float bia = in_b[col];
    #pragma unroll
    for (int i2 = 0; i2 < 4; ++i2)
      qkv[(mt*16 + mfr + i2)*QP + col] = acc[i2] + bia;
  }
  __syncthreads();

  // ---- P4: attention (2 threads per (h,i), 728 active) ; stage ff1 -> wA ----
  for (int e = tid; e < 2*DM*DM/8; e += NT) {     // ff1_w [128][64]
    int r = e >> 3, c8 = e & 7;
    stg8(wA, r, c8*8, &ff1_w[r*DM + c8*8], 128);
  }
  {
    const int q2   = tid >> 1;
    const int half = tid & 1;
    if (q2 < 4*NC) {
      const int h = q2 / NC;
      const int i = q2 - h*NC;
      const float* qr = &qkv[i*QP + h*16];
      float4 qa = *(const float4*)(qr+0),  qb = *(const float4*)(qr+4),
             qc = *(const float4*)(qr+8),  qd = *(const float4*)(qr+12);
      float4 oa = {0,0,0,0}, obv = {0,0,0,0}, ocv = {0,0,0,0}, odv = {0,0,0,0};
      float mrun = -3.0e38f, lrun = 0.0f;
      const int j0 = half ? 46 : 0;
      const int j1 = half ? NC : 46;
      for (int j = j0; j < j1; ++j) {
        const float* kr = &qkv[j*QP + DM + h*16];
        float4 ka = *(const float4*)(kr+0), kb = *(const float4*)(kr+4),
               kc = *(const float4*)(kr+8), kd = *(const float4*)(kr+12);
        float t0 = fmaf(qa.w,ka.w, fmaf(qa.z,ka.z, fmaf(qa.y,ka.y, qa.x*ka.x)));
        float t1 = fmaf(qb.w,kb.w, fmaf(qb.z,kb.z, fmaf(qb.y,kb.y, qb.x*kb.x)));
        float t2 = fmaf(qc.w,kc.w, fmaf(qc.z,kc.z, fmaf(qc.y,kc.y, qc.x*kc.x)));
        float t3 = fmaf(qd.w,kd.w, fmaf(qd.z,kd.z, fmaf(qd.y,kd.y, qd.x*kd.x)));
        float s = ((t0+t1)+(t2+t3)) * 0.25f;
        float mn = fmaxf(mrun, s);
        float sc = __expf(mrun - mn);
        float pw = __expf(s - mn);
        lrun = lrun*sc + pw;
        const float* vr = &qkv[j*QP + 2*DM + h*16];
        float4 va = *(const float4*)(vr+0), vb = *(const float4*)(vr+4),
               vc = *(const float4*)(vr+8), vd = *(const float4*)(vr+12);
        oa.x = oa.x*sc + pw*va.x;  oa.y = oa.y*sc + pw*va.y;
        oa.z = oa.z*sc + pw*va.z;  oa.w = oa.w*sc + pw*va.w;
        obv.x = obv.x*sc + pw*vb.x; obv.y = obv.y*sc + pw*vb.y;
        obv.z = obv.z*sc + pw*vb.z; obv.w = obv.w*sc + pw*vb.w;
        ocv.x = ocv.x*sc + pw*vc.x; ocv.y = ocv.y*sc + pw*vc.y;
        ocv.z = ocv.z*sc + pw*vc.z; ocv.w = ocv.w*sc + pw*vc.w;
        odv.x = odv.x*sc + pw*vd.x; odv.y = odv.y*sc + pw*vd.y;
        odv.z = odv.z*sc + pw*vd.z; odv.w = odv.w*sc + pw*vd.w;
        mrun = mn;
      }
      // merge the two halves (adjacent lanes)
      float mo = __shfl_xor(mrun, 1, 64);
      float lo = __shfl_xor(lrun, 1, 64);
      float mn2 = fmaxf(mrun, mo);
      float se = __expf(mrun - mn2);
      float so = __expf(mo - mn2);
      float lm = lrun*se + lo*so;
      #define MRG(c) c = c*se + __shfl_xor(c, 1, 64)*so
      MRG(oa.x); MRG(oa.y); MRG(oa.z); MRG(oa.w);
      MRG(obv.x); MRG(obv.y); MRG(obv.z); MRG(obv.w);
      MRG(ocv.x); MRG(ocv.y); MRG(ocv.z); MRG(ocv.w);
      MRG(odv.x); MRG(odv.y); MRG(odv.z); MRG(odv.w);
      #undef MRG
      float inv = 1.0f / lm;
      float4 w0 = half ? ocv : oa;
      float4 w1 = half ? odv : obv;
      short8 ow;
      ow[0]=f2bf(w0.x*inv); ow[1]=f2bf(w0.y*inv); ow[2]=f2bf(w0.z*inv); ow[3]=f2bf(w0.w*inv);
      ow[4]=f2bf(w1.x*inv); ow[5]=f2bf(w1.y*inv); ow[6]=f2bf(w1.z*inv); ow[7]=f2bf(w1.w*inv);
      *(short8*)((char*)ab16 + SWZ(i, h*16 + half*8, 128)) = ow;
    }
  }
  __syncthreads();

  // ---- P5: out-proj MFMA: hbuf += o @ out_w^T + out_b ----
  for (int t = wid; t < 24; t += NW) {
    int mt = t >> 2, nt = t & 3;
    int ar = mt*16 + l15, br = nt*16 + l15;
    f32x4 acc = {0.f,0.f,0.f,0.f};
    #pragma unroll
    for (int kk = 0; kk < 2; ++kk) {
      short8 a = ldfrag128(ab16,       ar, kk*32 + kfr);
      short8 w = ldfrag128((short*)wB, br, kk*32 + kfr);
      acc = __builtin_amdgcn_mfma_f32_16x16x32_bf16(a, w, acc, 0, 0, 0);
    }
    int col = nt*16 + l15;
    float ob = out_b[col];
    #pragma unroll
    for (int i2 = 0; i2 < 4; ++i2) {
      int m = mt*16 + mfr + i2;
      hbuf[m*HP + col] += acc[i2] + ob;
    }
  }
  __syncthreads();

  // ---- P6: LN2 -> ab16 ; stage ff2 -> wB ----
  for (int e = tid; e < DM*CIN/8; e += NT) {      // ff2_w [64][128]
    int r = e >> 4, c8 = e & 15;
    stg8(wB, r, c8*8, &ff2_w[r*CIN + c8*8], 256);
  }
  {
    const float g = ln2_g[lane], bb = ln2_b[lane];
    for (int i = wid; i < NC; i += NW) {
      float v = hbuf[i*HP + lane];
      float s = v, sq = v*v;
      #pragma unroll
      for (int off = 32; off >= 1; off >>= 1) {
        s  += __shfl_xor(s, off, 64);
        sq += __shfl_xor(sq, off, 64);
      }
      float m  = s * (1.0f/64.0f);
      float vr = sq * (1.0f/64.0f) - m*m;
      float rs = rsqrtf(vr + 1e-5f);
      stb16_128(ab16, i, lane, (v - m) * rs * g + bb);
    }
  }
  __syncthreads();

  // ---- P7: ff1 MFMA (N=128, K=64) -> f1 bf16 in arena ----
  short* f1 = (short*)arena;                      // [96][128] bf16 swz PB=256
  for (int t = wid; t < 48; t += NW) {
    int mt = t >> 3, nt = t & 7;
    int ar = mt*16 + l15, br = nt*16 + l15;
    f32x4 acc = {0.f,0.f,0.f,0.f};
    #pragma unroll
    for (int kk = 0; kk < 2; ++kk) {
      short8 a = ldfrag128(ab16, ar, kk*32 + kfr);
      short8 w = ldfrag128(wA,   br, kk*32 + kfr);
      acc = __builtin_amdgcn_mfma_f32_16x16x32_bf16(a, w, acc, 0, 0, 0);
    }
    int col = nt*16 + l15;
    float bia = ff1_b[col];
    #pragma unroll
    for (int i2 = 0; i2 < 4; ++i2) {
      int m = mt*16 + mfr + i2;
      *(short*)((char*)f1 + SWZ(m, col, 256)) = f2bf(fmaxf(acc[i2] + bia, 0.f));
    }
  }
  __syncthreads();

  // ---- P8: ff2 MFMA (K=128): h_new = hbuf + f1@W^T + b -> ab16 bf16 ; stage from/to -> wA ----
  for (int e = tid; e < 2*DM*DM/8; e += NT) {     // [128][64]: rows 0..63 from, 64..127 to
    int r = e >> 3, c8 = e & 7;
    const float* src = (r < DM) ? &from_w[r*DM + c8*8] : &to_w[(r-DM)*DM + c8*8];
    stg8(wA, r, c8*8, src, 128);
  }
  for (int t = wid; t < 24; t += NW) {
    int mt = t >> 2, nt = t & 3;
    int ar = mt*16 + l15, br = nt*16 + l15;
    f32x4 acc = {0.f,0.f,0.f,0.f};
    #pragma unroll
    for (int kk = 0; kk < 4; ++kk) {
      short8 a = ldfrag256(f1, ar, kk*32 + kfr);
      short8 w = ldfrag256(wB, br, kk*32 + kfr);
      acc = __builtin_amdgcn_mfma_f32_16x16x32_bf16(a, w, acc, 0, 0, 0);
    }
    int col = nt*16 + l15;
    float bia = ff2_b[col];
    #pragma unroll
    for (int i2 = 0; i2 < 4; ++i2) {
      int m = mt*16 + mfr + i2;
      stb16_128(ab16, m, col, hbuf[m*HP + col] + acc[i2] + bia);
    }
  }
  __syncthreads();

  // ---- P9: from/to MFMA (N=128, K=64) -> F, T bf16 ----
  short* Fb = (short*)arena;                      // [96][64] bf16 swz PB=128
  short* Tb = (short*)arena + 6144;               // [96][64] bf16 swz PB=128
  for (int t = wid; t < 48; t += NW) {
    int mt = t >> 3, nt = t & 7;
    int ar = mt*16 + l15, br = nt*16 + l15;
    f32x4 acc = {0.f,0.f,0.f,0.f};
    #pragma unroll
    for (int kk = 0; kk < 2; ++kk) {
      short8 a = ldfrag128(ab16, ar, kk*32 + kfr);
      short8 w = ldfrag128(wA,   br, kk*32 + kfr);
      acc = __builtin_amdgcn_mfma_f32_16x16x32_bf16(a, w, acc, 0, 0, 0);
    }
    int col = nt*16 + l15;
    if (nt < 4) {
      float bia = from_b[col];
      #pragma unroll
      for (int i2 = 0; i2 < 4; ++i2)
        stb16_128(Fb, mt*16 + mfr + i2, col, acc[i2] + bia);
    } else {
      int c2 = col - 64;
      float bia = to_b[c2];
      #pragma unroll
      for (int i2 = 0; i2 < 4; ++i2)
        stb16_128(Tb, mt*16 + mfr + i2, c2, acc[i2] + bia);
    }
  }
  __syncthreads();

  // ---- P10: gram MFMA: G = F @ T^T (96x96, K=64) ----
  float* G = arena + 6144;                        // [96][96] fp32
  for (int t = wid; t < 36; t += NW) {
    int mt = t / 6, nt = t - mt*6;
    int ar = mt*16 + l15, br = nt*16 + l15;
    f32x4 acc = {0.f,0.f,0.f,0.f};
    #pragma unroll
    for (int kk = 0; kk < 2; ++kk) {
      short8 a = ldfrag128(Fb, ar, kk*32 + kfr);
      short8 w = ldfrag128(Tb, br, kk*32 + kfr);
      acc = __builtin_amdgcn_mfma_f32_16x16x32_bf16(a, w, acc, 0, 0, 0);
    }
    int col = nt*16 + l15;
    #pragma unroll
    for (int i2 = 0; i2 < 4; ++i2)
      G[(mt*16 + mfr + i2)*GP + col] = acc[i2];
  }
  __syncthreads();

  // ---- P11: logits gather ----
  {
    float* ob = out + (size_t)b * NMOV;
    for (int m = tid; m < NMOV; m += NT) {
      ob[m] = G[move_from[m]*GP + move_to[m]] + move_bias[m];
    }
  }
}

extern "C" void kernel_launch(void* const* d_in, const int* in_sizes, int n_in,
                              void* d_out, int out_size, void* d_ws, size_t ws_size,
                              hipStream_t stream) {
  const float* x        = (const float*)d_in[0];
  const float* embed_w  = (const float*)d_in[1];
  const float* embed_b  = (const float*)d_in[2];
  const float* pos      = (const float*)d_in[3];
  const float* in_w     = (const float*)d_in[4];
  const float* in_b     = (const float*)d_in[5];
  const float* out_w    = (const float*)d_in[6];
  const float* out_b    = (const float*)d_in[7];
  const float* ln1_g    = (const float*)d_in[8];
  const float* ln1_b    = (const float*)d_in[9];
  const float* ln2_g    = (const float*)d_in[10];
  const float* ln2_b    = (const float*)d_in[11];
  const float* ff1_w    = (const float*)d_in[12];
  const float* ff1_b    = (const float*)d_in[13];
  const float* ff2_w    = (const float*)d_in[14];
  const float* ff2_b    = (const float*)d_in[15];
  const float* from_w   = (const float*)d_in[16];
  const float* from_b   = (const float*)d_in[17];
  const float* to_w     = (const float*)d_in[18];
  const float* to_b     = (const float*)d_in[19];
  const float* move_bias= (const float*)d_in[20];
  const int*   move_from= (const int*)d_in[21];
  const int*   move_to  = (const int*)d_in[22];

  int B = in_sizes[0] / (CIN * 121);
  policy_fused<<<dim3(B), dim3(NT), 0, stream>>>(
      x, embed_w, embed_b, pos, in_w, in_b, out_w, out_b,
      ln1_g, ln1_b, ln2_g, ln2_b, ff1_w, ff1_b, ff2_w, ff2_b,
      from_w, from_b, to_w, to_b, move_bias, move_from, move_to,
      (float*)d_out);
}